// Round 5
// baseline (1570.829 us; speedup 1.0000x reference)
//
#include <hip/hip_runtime.h>
#include <hip/hip_bf16.h>
#include <math.h>

#define S 4096
#define B 32
#define H 512
#define NSC 16

typedef float f32x16 __attribute__((ext_vector_type(16)));
typedef short s16x8 __attribute__((ext_vector_type(8)));

__device__ __forceinline__ unsigned short f2bf(float x) {
  return __builtin_bit_cast(unsigned short, __float2bfloat16(x));
}
__device__ __forceinline__ float bf2f(unsigned short h) {
  return __builtin_bit_cast(float, ((unsigned)h) << 16);
}
__device__ __forceinline__ float tanh_fast(float x) {
  float e = __expf(2.0f * x);
  return 1.0f - 2.0f / (e + 1.0f);
}

// K0: repack We = attn_W[:, H:] into 32x32x16 MFMA B-fragment order, bf16 hi/lo.
// frag[((n*32+ks)*64+lane)*8+j] = We^T[k][o]; o = n*32+(lane&31), k = ks*16+(lane>>5)*8+j
__global__ __launch_bounds__(256) void k_wfrag(const float* __restrict__ W,
                                               unsigned short* __restrict__ WH,
                                               unsigned short* __restrict__ WL) {
  int id = blockIdx.x * 256 + threadIdx.x;   // 0..32767
  int lane = id & 63, ks = (id >> 6) & 31, n = id >> 11;
  int o = n * 32 + (lane & 31);
  int kb = ks * 16 + (lane >> 5) * 8;
  const float* src = W + (size_t)o * (2 * H) + H + kb;
  s16x8 h, l;
#pragma unroll
  for (int j = 0; j < 8; ++j) {
    float x = src[j];
    unsigned short hb = f2bf(x);
    h[j] = (short)hb;
    l[j] = (short)f2bf(x - bf2f(hb));
  }
  *(s16x8*)(WH + (size_t)id * 8) = h;
  *(s16x8*)(WL + (size_t)id * 8) = l;
}

// K1: hprojT[o][b] = sum_h hidden[b][h]*attn_W[o][h] + bias[o]  (TRANSPOSED out)
__global__ __launch_bounds__(256) void k_hproj(const float* __restrict__ hidden,
                                               const float* __restrict__ W,
                                               const float* __restrict__ bias,
                                               float* __restrict__ hprojT) {
  int blk = blockIdx.x;
  int b = blk >> 3, oc = blk & 7;
  int t = threadIdx.x;
  int o = oc * 64 + (t >> 2);
  int kq = t & 3;
  const float* hrow = hidden + b * H + kq * 128;
  const float* wrow = W + (size_t)o * (2 * H) + kq * 128;
  float p = 0.f;
#pragma unroll 4
  for (int k = 0; k < 128; ++k) p = fmaf(hrow[k], wrow[k], p);
  p += __shfl_xor(p, 1);
  p += __shfl_xor(p, 2);
  if (kq == 0) hprojT[o * B + b] = p + bias[o];
}

#define MFMA32(a, b, c) __builtin_amdgcn_mfma_f32_32x32x16_bf16(a, b, c, 0, 0, 0)

// K2: fused e_proj (bf16x3, 32x32x16 MFMA) + tanh + v-dot -> scores[b][s]
// Wave owns 32 consecutive sb-rows (sb = s*B+b), full K=512 A hi/lo in regs.
// Block = 4 waves = 128 rows; n-loop over 16 col-tiles of 32.
__global__ __launch_bounds__(256, 1) void k_scores(const float* __restrict__ enc,
                                                   const s16x8* __restrict__ WH8,
                                                   const s16x8* __restrict__ WL8,
                                                   const float* __restrict__ hprojT,
                                                   const float* __restrict__ vW,
                                                   float* __restrict__ scores) {
  int t = threadIdx.x;
  int w = t >> 6, lane = t & 63;
  int wbase = blockIdx.x * 128 + w * 32;   // first sb-row (multiple of 32 -> b == m)
  int arow = wbase + (lane & 31);          // A-row this lane feeds
  int half = lane >> 5;                    // k-octet selector

  // A fragments hi/lo for all 32 k-steps: enc[arow][ks*16 + half*8 + j]
  s16x8 ah[32], al[32];
  {
    const float* ap = enc + (size_t)arow * H + half * 8;
#pragma unroll
    for (int ks = 0; ks < 32; ++ks) {
      float4 x0 = *(const float4*)(ap + ks * 16);
      float4 x1 = *(const float4*)(ap + ks * 16 + 4);
      float xs[8] = {x0.x, x0.y, x0.z, x0.w, x1.x, x1.y, x1.z, x1.w};
      s16x8 h, l;
#pragma unroll
      for (int j = 0; j < 8; ++j) {
        unsigned short hb = f2bf(xs[j]);
        h[j] = (short)hb;
        l[j] = (short)f2bf(xs[j] - bf2f(hb));
      }
      ah[ks] = h;
      al[ks] = l;
    }
  }

  float p[16];
#pragma unroll
  for (int r = 0; r < 16; ++r) p[r] = 0.f;

  for (int n = 0; n < 16; ++n) {
    f32x16 chh = {}, chl = {}, clh = {};
    const s16x8* bh = WH8 + (size_t)(n * 32) * 64 + lane;
    const s16x8* bl = WL8 + (size_t)(n * 32) * 64 + lane;
    // two half-tiles of 16 ks each, bare barrier between keeps the block's
    // 4 waves (4 SIMDs, shared L1) in lockstep through the 32KB window.
    __builtin_amdgcn_s_barrier();
#pragma unroll
    for (int ks = 0; ks < 16; ++ks) {
      s16x8 b0 = bh[ks * 64], b1 = bl[ks * 64];
      chh = MFMA32(ah[ks], b0, chh);
      chl = MFMA32(ah[ks], b1, chl);
      clh = MFMA32(al[ks], b0, clh);
    }
    __builtin_amdgcn_s_barrier();
#pragma unroll
    for (int ks = 16; ks < 32; ++ks) {
      s16x8 b0 = bh[ks * 64], b1 = bl[ks * 64];
      chh = MFMA32(ah[ks], b0, chh);
      chl = MFMA32(ah[ks], b1, chl);
      clh = MFMA32(al[ks], b0, clh);
    }
    // tail: e = chh+chl+clh + hprojT[o][m];  p[reg] += vW[o]*tanh(e)
    int o = n * 32 + (lane & 31);
    float vw = vW[o];
    const float4* hp4 = (const float4*)(hprojT + o * B + half * 4);
    float4 h0 = hp4[0], h1 = hp4[2], h2 = hp4[4], h3 = hp4[6];
    float hr[16] = {h0.x, h0.y, h0.z, h0.w, h1.x, h1.y, h1.z, h1.w,
                    h2.x, h2.y, h2.z, h2.w, h3.x, h3.y, h3.z, h3.w};
#pragma unroll
    for (int r = 0; r < 16; ++r) {
      float e = (chh[r] + chl[r]) + clh[r] + hr[r];
      p[r] += vw * tanh_fast(e);
    }
  }

  // reduce each p[r] over the 32 col-lanes; lanes 0 and 32 hold results
#pragma unroll
  for (int off = 1; off < 32; off <<= 1) {
#pragma unroll
    for (int r = 0; r < 16; ++r) p[r] += __shfl_xor(p[r], off);
  }
  if ((lane & 31) == 0) {
    int srow = wbase >> 5;   // same s for all 32 rows of this wave
#pragma unroll
    for (int r = 0; r < 16; ++r) {
      int m = (r & 3) + 8 * (r >> 2) + 4 * half;  // row in wave = b index
      scores[(size_t)m * S + srow] = p[r];
    }
  }
}

// K3: softmax over s for each b
__global__ __launch_bounds__(256) void k_softmax(const float* __restrict__ scores,
                                                 float* __restrict__ outw) {
  int b = blockIdx.x, t = threadIdx.x;
  const float* row = scores + (size_t)b * S;
  float* wrow = outw + (size_t)b * S;
  float m = -1e30f;
  for (int s = t; s < S; s += 256) m = fmaxf(m, row[s]);
#pragma unroll
  for (int off = 32; off; off >>= 1) m = fmaxf(m, __shfl_xor(m, off));
  __shared__ float red[4];
  __shared__ float red2[4];
  int wv = t >> 6, ln = t & 63;
  if (ln == 0) red[wv] = m;
  __syncthreads();
  m = fmaxf(fmaxf(red[0], red[1]), fmaxf(red[2], red[3]));
  float sum = 0.f;
  for (int s = t; s < S; s += 256) {
    float e = __expf(row[s] - m);
    wrow[s] = e;
    sum += e;
  }
#pragma unroll
  for (int off = 32; off; off >>= 1) sum += __shfl_xor(sum, off);
  if (ln == 0) red2[wv] = sum;
  __syncthreads();
  sum = red2[0] + red2[1] + red2[2] + red2[3];
  float inv = 1.f / sum;
  for (int s = t; s < S; s += 256) wrow[s] *= inv;
}

// K4: partial context sums over s-chunks: part[b][sc][h], float2-vectorized
__global__ __launch_bounds__(256) void k_ctxpart(const float* __restrict__ enc,
                                                 const float* __restrict__ w,
                                                 float* __restrict__ part) {
  int b = blockIdx.x, sc = blockIdx.y, t = threadIdx.x;
  const float* wrow = w + (size_t)b * S + sc * (S / NSC);
  float2 acc = {0.f, 0.f};
  for (int ss = 0; ss < S / NSC; ss += 2) {
    int s = sc * (S / NSC) + ss;
    float w0 = wrow[ss], w1 = wrow[ss + 1];
    float2 e0 = ((const float2*)(enc + ((size_t)s * B + b) * H))[t];
    float2 e1 = ((const float2*)(enc + ((size_t)(s + 1) * B + b) * H))[t];
    acc.x = fmaf(w0, e0.x, acc.x);
    acc.y = fmaf(w0, e0.y, acc.y);
    acc.x = fmaf(w1, e1.x, acc.x);
    acc.y = fmaf(w1, e1.y, acc.y);
  }
  ((float2*)(part + ((size_t)b * NSC + sc) * H))[t] = acc;
}

// K5: reduce partials -> context[b][h]
__global__ __launch_bounds__(256) void k_ctxsum(const float* __restrict__ part,
                                                float* __restrict__ ctx) {
  int idx = blockIdx.x * 256 + threadIdx.x;
  int b = idx >> 9, h = idx & 511;
  float sum = 0.f;
#pragma unroll
  for (int sc = 0; sc < NSC; ++sc) sum += part[((size_t)b * NSC + sc) * H + h];
  ctx[idx] = sum;
}

extern "C" void kernel_launch(void* const* d_in, const int* in_sizes, int n_in,
                              void* d_out, int out_size, void* d_ws, size_t ws_size,
                              hipStream_t stream) {
  const float* hidden = (const float*)d_in[0];   // (B,H)
  const float* enc    = (const float*)d_in[1];   // (S,B,H)
  const float* W      = (const float*)d_in[2];   // (H, 2H)
  const float* bias   = (const float*)d_in[3];   // (H,)
  const float* vW     = (const float*)d_in[4];   // (1,H)

  float* out   = (float*)d_out;
  float* ctx   = out;            // B*H
  float* attnw = out + B * H;    // B*S

  float* ws      = (float*)d_ws;
  float* hprojT  = ws;                      // B*H     = 16384 f (stored [o][b])
  float* scores  = ws + B * H;              // B*S     = 131072 f
  // union region (1 MB): WeFrag hi/lo during k_scores, then part for context
  float* region = scores + (size_t)B * S;   // 262144 f = 1 MB
  unsigned short* WH = (unsigned short*)region;                 // 512 KB
  unsigned short* WL = (unsigned short*)(region + 131072);      // 512 KB
  float* part = region;                                         // B*NSC*H

  k_wfrag<<<128, 256, 0, stream>>>(W, WH, WL);
  k_hproj<<<256, 256, 0, stream>>>(hidden, W, bias, hprojT);
  k_scores<<<(S * B) / 128, 256, 0, stream>>>(enc, (const s16x8*)WH, (const s16x8*)WL,
                                              hprojT, vW, scores);
  k_softmax<<<B, 256, 0, stream>>>(scores, attnw);
  k_ctxpart<<<dim3(B, NSC), 256, 0, stream>>>(enc, attnw, part);
  k_ctxsum<<<(B * H) / 256, 256, 0, stream>>>(part, ctx);
}

// Round 7
// 674.130 us; speedup vs baseline: 2.3302x; 2.3302x over previous
//
#include <hip/hip_runtime.h>
#include <hip/hip_bf16.h>
#include <math.h>

#define S 4096
#define B 32
#define H 512
#define NSC 16

typedef float f32x16 __attribute__((ext_vector_type(16)));
typedef short s16x8 __attribute__((ext_vector_type(8)));

__device__ __forceinline__ unsigned short f2bf(float x) {
  return __builtin_bit_cast(unsigned short, __float2bfloat16(x));
}
__device__ __forceinline__ float bf2f(unsigned short h) {
  return __builtin_bit_cast(float, ((unsigned)h) << 16);
}
__device__ __forceinline__ float tanh_fast(float x) {
  float e = __expf(2.0f * x);
  return 1.0f - 2.0f / (e + 1.0f);
}

// async global->LDS, 16B per lane; LDS dest = uniform base + lane*16 (HW-added)
#define GLOAD_LDS16(g, l) __builtin_amdgcn_global_load_lds( \
    (const __attribute__((address_space(1))) void*)(g),     \
    (__attribute__((address_space(3))) void*)(l), 16, 0, 0)

// K0: repack We = attn_W[:, H:] into 32x32x16 MFMA B-fragment order, bf16 hi/lo.
// frag[((n*32+ks)*64+lane)*8+j] = We^T[k][o]; o = n*32+(lane&31), k = ks*16+(lane>>5)*8+j
__global__ __launch_bounds__(256) void k_wfrag(const float* __restrict__ W,
                                               unsigned short* __restrict__ WH,
                                               unsigned short* __restrict__ WL) {
  int id = blockIdx.x * 256 + threadIdx.x;   // 0..32767
  int lane = id & 63, ks = (id >> 6) & 31, n = id >> 11;
  int o = n * 32 + (lane & 31);
  int kb = ks * 16 + (lane >> 5) * 8;
  const float* src = W + (size_t)o * (2 * H) + H + kb;
  s16x8 h, l;
#pragma unroll
  for (int j = 0; j < 8; ++j) {
    float x = src[j];
    unsigned short hb = f2bf(x);
    h[j] = (short)hb;
    l[j] = (short)f2bf(x - bf2f(hb));
  }
  *(s16x8*)(WH + (size_t)id * 8) = h;
  *(s16x8*)(WL + (size_t)id * 8) = l;
}

// K1: hprojT[o][b] = sum_h hidden[b][h]*attn_W[o][h] + bias[o]  (TRANSPOSED out)
__global__ __launch_bounds__(256) void k_hproj(const float* __restrict__ hidden,
                                               const float* __restrict__ W,
                                               const float* __restrict__ bias,
                                               float* __restrict__ hprojT) {
  int blk = blockIdx.x;
  int b = blk >> 3, oc = blk & 7;
  int t = threadIdx.x;
  int o = oc * 64 + (t >> 2);
  int kq = t & 3;
  const float* hrow = hidden + b * H + kq * 128;
  const float* wrow = W + (size_t)o * (2 * H) + kq * 128;
  float p = 0.f;
#pragma unroll 4
  for (int k = 0; k < 128; ++k) p = fmaf(hrow[k], wrow[k], p);
  p += __shfl_xor(p, 1);
  p += __shfl_xor(p, 2);
  if (kq == 0) hprojT[o * B + b] = p + bias[o];
}

#define MFMA32(a, b, c) __builtin_amdgcn_mfma_f32_32x32x16_bf16(a, b, c, 0, 0, 0)

// wave w stages its 8KB slice of phase ph (16KB hi + 16KB lo) into dstbuf
#define STAGE(dstbuf, ph)                                          \
  {                                                                \
    const char* gh_ = WHb + (size_t)(ph) * 16384;                  \
    const char* gl_ = WLb + (size_t)(ph) * 16384;                  \
    _Pragma("unroll")                                              \
    for (int i_ = 0; i_ < 4; ++i_) {                               \
      int co_ = (w * 4 + i_) * 1024;                               \
      GLOAD_LDS16(gh_ + co_ + lane * 16, dstbuf + co_);            \
      GLOAD_LDS16(gl_ + co_ + lane * 16, dstbuf + 16384 + co_);    \
    }                                                              \
  }

// K2: fused e_proj (bf16x3, 32x32x16 MFMA) + tanh + v-dot -> scores[b][s]
// Wave owns 32 consecutive sb-rows, full K=512 A hi/lo in regs.
// B-fragments double-buffered in LDS, 2-phase pipeline (stage(next); compute(cur)).
// Phase p = 2n+h: h=0 reads Bb0, h=1 reads Bb1 (parity-static buffers).
__global__ __launch_bounds__(256, 1) void k_scores(const float* __restrict__ enc,
                                                   const char* __restrict__ WHb,
                                                   const char* __restrict__ WLb,
                                                   const float* __restrict__ hprojT,
                                                   const float* __restrict__ vW,
                                                   float* __restrict__ scores) {
  __shared__ char Bb0[32768];
  __shared__ char Bb1[32768];
  int t = threadIdx.x;
  int w = t >> 6, lane = t & 63;
  int wbase = blockIdx.x * 128 + w * 32;   // first sb-row (multiple of 32 -> b == m)
  int arow = wbase + (lane & 31);
  int half = lane >> 5;

  // issue phase-0 staging first; its latency hides under the A-frag build
  STAGE(Bb0, 0);

  // A fragments hi/lo for all 32 k-steps: enc[arow][ks*16 + half*8 + j]
  s16x8 ah[32], al[32];
  {
    const float* ap = enc + (size_t)arow * H + half * 8;
#pragma unroll
    for (int ks = 0; ks < 32; ++ks) {
      float4 x0 = *(const float4*)(ap + ks * 16);
      float4 x1 = *(const float4*)(ap + ks * 16 + 4);
      float xs[8] = {x0.x, x0.y, x0.z, x0.w, x1.x, x1.y, x1.z, x1.w};
      s16x8 h, l;
#pragma unroll
      for (int j = 0; j < 8; ++j) {
        unsigned short hb = f2bf(xs[j]);
        h[j] = (short)hb;
        l[j] = (short)f2bf(xs[j] - bf2f(hb));
      }
      ah[ks] = h;
      al[ks] = l;
    }
  }

  float pr[16];
#pragma unroll
  for (int r = 0; r < 16; ++r) pr[r] = 0.f;

  __syncthreads();   // phase-0 staging complete (vmcnt(0) implied)

  for (int n = 0; n < 16; ++n) {
    f32x16 chh = {}, chl = {}, clh = {};
    // ---- phase h=0: stage phase 2n+1 -> Bb1; compute ks 0..15 from Bb0
    STAGE(Bb1, 2 * n + 1);
#pragma unroll
    for (int ks = 0; ks < 16; ++ks) {
      s16x8 b0 = *(const s16x8*)(Bb0 + ks * 1024 + lane * 16);
      s16x8 b1 = *(const s16x8*)(Bb0 + 16384 + ks * 1024 + lane * 16);
      chh = MFMA32(ah[ks], b0, chh);
      chl = MFMA32(ah[ks], b1, chl);
      clh = MFMA32(al[ks], b0, clh);
    }
    __syncthreads();
    // ---- phase h=1: stage phase 2n+2 -> Bb0 (if any); compute ks 16..31 from Bb1
    if (n < 15) STAGE(Bb0, 2 * n + 2);
#pragma unroll
    for (int ks = 0; ks < 16; ++ks) {
      s16x8 b0 = *(const s16x8*)(Bb1 + ks * 1024 + lane * 16);
      s16x8 b1 = *(const s16x8*)(Bb1 + 16384 + ks * 1024 + lane * 16);
      chh = MFMA32(ah[16 + ks], b0, chh);
      chl = MFMA32(ah[16 + ks], b1, chl);
      clh = MFMA32(al[16 + ks], b0, clh);
    }
    // tail: e = chh+chl+clh + hprojT[o][m];  pr[reg] += vW[o]*tanh(e)
    {
      int o = n * 32 + (lane & 31);
      float vw = vW[o];
      const float4* hp4 = (const float4*)(hprojT + o * B + half * 4);
      float4 h0 = hp4[0], h1 = hp4[2], h2 = hp4[4], h3 = hp4[6];
      float hr[16] = {h0.x, h0.y, h0.z, h0.w, h1.x, h1.y, h1.z, h1.w,
                      h2.x, h2.y, h2.z, h2.w, h3.x, h3.y, h3.z, h3.w};
#pragma unroll
      for (int r = 0; r < 16; ++r) {
        float e = (chh[r] + chl[r]) + clh[r] + hr[r];
        pr[r] += vw * tanh_fast(e);
      }
    }
    __syncthreads();
  }

  // reduce each pr[r] over the 32 col-lanes; lanes 0 and 32 hold results
#pragma unroll
  for (int off = 1; off < 32; off <<= 1) {
#pragma unroll
    for (int r = 0; r < 16; ++r) pr[r] += __shfl_xor(pr[r], off);
  }
  if ((lane & 31) == 0) {
    int srow = wbase >> 5;   // same s for all 32 rows of this wave
#pragma unroll
    for (int r = 0; r < 16; ++r) {
      int m = (r & 3) + 8 * (r >> 2) + 4 * half;  // row in wave = b index
      scores[(size_t)m * S + srow] = pr[r];
    }
  }
}

// K3: softmax over s for each b
__global__ __launch_bounds__(256) void k_softmax(const float* __restrict__ scores,
                                                 float* __restrict__ outw) {
  int b = blockIdx.x, t = threadIdx.x;
  const float* row = scores + (size_t)b * S;
  float* wrow = outw + (size_t)b * S;
  float m = -1e30f;
  for (int s = t; s < S; s += 256) m = fmaxf(m, row[s]);
#pragma unroll
  for (int off = 32; off; off >>= 1) m = fmaxf(m, __shfl_xor(m, off));
  __shared__ float red[4];
  __shared__ float red2[4];
  int wv = t >> 6, ln = t & 63;
  if (ln == 0) red[wv] = m;
  __syncthreads();
  m = fmaxf(fmaxf(red[0], red[1]), fmaxf(red[2], red[3]));
  float sum = 0.f;
  for (int s = t; s < S; s += 256) {
    float e = __expf(row[s] - m);
    wrow[s] = e;
    sum += e;
  }
#pragma unroll
  for (int off = 32; off; off >>= 1) sum += __shfl_xor(sum, off);
  if (ln == 0) red2[wv] = sum;
  __syncthreads();
  sum = red2[0] + red2[1] + red2[2] + red2[3];
  float inv = 1.f / sum;
  for (int s = t; s < S; s += 256) wrow[s] *= inv;
}

// K4: partial context sums over s-chunks: part[b][sc][h], float2-vectorized
__global__ __launch_bounds__(256) void k_ctxpart(const float* __restrict__ enc,
                                                 const float* __restrict__ w,
                                                 float* __restrict__ part) {
  int b = blockIdx.x, sc = blockIdx.y, t = threadIdx.x;
  const float* wrow = w + (size_t)b * S + sc * (S / NSC);
  float2 acc = {0.f, 0.f};
  for (int ss = 0; ss < S / NSC; ss += 2) {
    int s = sc * (S / NSC) + ss;
    float w0 = wrow[ss], w1 = wrow[ss + 1];
    float2 e0 = ((const float2*)(enc + ((size_t)s * B + b) * H))[t];
    float2 e1 = ((const float2*)(enc + ((size_t)(s + 1) * B + b) * H))[t];
    acc.x = fmaf(w0, e0.x, acc.x);
    acc.y = fmaf(w0, e0.y, acc.y);
    acc.x = fmaf(w1, e1.x, acc.x);
    acc.y = fmaf(w1, e1.y, acc.y);
  }
  ((float2*)(part + ((size_t)b * NSC + sc) * H))[t] = acc;
}

// K5: reduce partials -> context[b][h]
__global__ __launch_bounds__(256) void k_ctxsum(const float* __restrict__ part,
                                                float* __restrict__ ctx) {
  int idx = blockIdx.x * 256 + threadIdx.x;
  int b = idx >> 9, h = idx & 511;
  float sum = 0.f;
#pragma unroll
  for (int sc = 0; sc < NSC; ++sc) sum += part[((size_t)b * NSC + sc) * H + h];
  ctx[idx] = sum;
}

extern "C" void kernel_launch(void* const* d_in, const int* in_sizes, int n_in,
                              void* d_out, int out_size, void* d_ws, size_t ws_size,
                              hipStream_t stream) {
  const float* hidden = (const float*)d_in[0];   // (B,H)
  const float* enc    = (const float*)d_in[1];   // (S,B,H)
  const float* W      = (const float*)d_in[2];   // (H, 2H)
  const float* bias   = (const float*)d_in[3];   // (H,)
  const float* vW     = (const float*)d_in[4];   // (1,H)

  float* out   = (float*)d_out;
  float* ctx   = out;            // B*H
  float* attnw = out + B * H;    // B*S

  float* ws      = (float*)d_ws;
  float* hprojT  = ws;                      // B*H     = 16384 f (stored [o][b])
  float* scores  = ws + B * H;              // B*S     = 131072 f
  // union region (1 MB): WeFrag hi/lo during k_scores, then part for context
  float* region = scores + (size_t)B * S;   // 262144 f = 1 MB
  unsigned short* WH = (unsigned short*)region;                 // 512 KB
  unsigned short* WL = (unsigned short*)(region + 131072);      // 512 KB
  float* part = region;                                         // B*NSC*H

  k_wfrag<<<128, 256, 0, stream>>>(W, WH, WL);
  k_hproj<<<256, 256, 0, stream>>>(hidden, W, bias, hprojT);
  k_scores<<<(S * B) / 128, 256, 0, stream>>>(enc, (const char*)WH, (const char*)WL,
                                              hprojT, vW, scores);
  k_softmax<<<B, 256, 0, stream>>>(scores, attnw);
  k_ctxpart<<<dim3(B, NSC), 256, 0, stream>>>(enc, attnw, part);
  k_ctxsum<<<(B * H) / 256, 256, 0, stream>>>(part, ctx);
}

// Round 8
// 641.949 us; speedup vs baseline: 2.4470x; 1.0501x over previous
//
#include <hip/hip_runtime.h>
#include <hip/hip_bf16.h>
#include <math.h>

#define S 4096
#define B 32
#define H 512
#define NSC 16

typedef float f32x16 __attribute__((ext_vector_type(16)));
typedef short s16x8 __attribute__((ext_vector_type(8)));

__device__ __forceinline__ unsigned short f2bf(float x) {
  return __builtin_bit_cast(unsigned short, __float2bfloat16(x));
}
__device__ __forceinline__ float bf2f(unsigned short h) {
  return __builtin_bit_cast(float, ((unsigned)h) << 16);
}
__device__ __forceinline__ float tanh_fast(float x) {
  float e = __expf(2.0f * x);
  return 1.0f - 2.0f / (e + 1.0f);
}

// async global->LDS, 16B per lane; LDS dest = uniform base + lane*16 (HW-added)
#define GLOAD_LDS16(g, l) __builtin_amdgcn_global_load_lds( \
    (const __attribute__((address_space(1))) void*)(g),     \
    (__attribute__((address_space(3))) void*)(l), 16, 0, 0)

// K0: repack We = attn_W[:, H:] into 32x32x16 MFMA B-fragment order, bf16 hi/lo.
// frag[((n*32+ks)*64+lane)*8+j] = We^T[k][o]; o = n*32+(lane&31), k = ks*16+(lane>>5)*8+j
__global__ __launch_bounds__(256) void k_wfrag(const float* __restrict__ W,
                                               unsigned short* __restrict__ WH,
                                               unsigned short* __restrict__ WL) {
  int id = blockIdx.x * 256 + threadIdx.x;   // 0..32767
  int lane = id & 63, ks = (id >> 6) & 31, n = id >> 11;
  int o = n * 32 + (lane & 31);
  int kb = ks * 16 + (lane >> 5) * 8;
  const float* src = W + (size_t)o * (2 * H) + H + kb;
  s16x8 h, l;
#pragma unroll
  for (int j = 0; j < 8; ++j) {
    float x = src[j];
    unsigned short hb = f2bf(x);
    h[j] = (short)hb;
    l[j] = (short)f2bf(x - bf2f(hb));
  }
  *(s16x8*)(WH + (size_t)id * 8) = h;
  *(s16x8*)(WL + (size_t)id * 8) = l;
}

// K1: hprojT[o][b] = sum_h hidden[b][h]*attn_W[o][h] + bias[o]  (TRANSPOSED out)
__global__ __launch_bounds__(256) void k_hproj(const float* __restrict__ hidden,
                                               const float* __restrict__ W,
                                               const float* __restrict__ bias,
                                               float* __restrict__ hprojT) {
  int blk = blockIdx.x;
  int b = blk >> 3, oc = blk & 7;
  int t = threadIdx.x;
  int o = oc * 64 + (t >> 2);
  int kq = t & 3;
  const float* hrow = hidden + b * H + kq * 128;
  const float* wrow = W + (size_t)o * (2 * H) + kq * 128;
  float p = 0.f;
#pragma unroll 4
  for (int k = 0; k < 128; ++k) p = fmaf(hrow[k], wrow[k], p);
  p += __shfl_xor(p, 1);
  p += __shfl_xor(p, 2);
  if (kq == 0) hprojT[o * B + b] = p + bias[o];
}

#define MFMA32(a, b, c) __builtin_amdgcn_mfma_f32_32x32x16_bf16(a, b, c, 0, 0, 0)

// stage sub-phase q (8 ks = 8KB hi + 8KB lo) into ring slot q&3; 4 loads/wave
#define SSTAGE(q)                                                        \
  {                                                                      \
    int q_ = (q);                                                        \
    char* rb_ = Bb + (q_ & 3) * 16384;                                   \
    const char* gh_ = WHb + (size_t)q_ * 8192 + w * 2048;                \
    const char* gl_ = WLb + (size_t)q_ * 8192 + w * 2048;                \
    GLOAD_LDS16(gh_ + lane * 16, rb_ + w * 2048);                        \
    GLOAD_LDS16(gh_ + 1024 + lane * 16, rb_ + w * 2048 + 1024);          \
    GLOAD_LDS16(gl_ + lane * 16, rb_ + 8192 + w * 2048);                 \
    GLOAD_LDS16(gl_ + 1024 + lane * 16, rb_ + 8192 + w * 2048 + 1024);   \
  }

// compute 8 k-steps of sub-phase q (ring slot q&3); SUB must be a literal 0..3
#define COMPUTE8(q, SUB)                                                 \
  {                                                                      \
    const char* rb_ = Bb + ((q) & 3) * 16384 + lane * 16;                \
    _Pragma("unroll")                                                    \
    for (int kl_ = 0; kl_ < 8; ++kl_) {                                  \
      s16x8 b0_ = *(const s16x8*)(rb_ + kl_ * 1024);                     \
      s16x8 b1_ = *(const s16x8*)(rb_ + 8192 + kl_ * 1024);              \
      chh = MFMA32(ah[(SUB) * 8 + kl_], b0_, chh);                       \
      chl = MFMA32(ah[(SUB) * 8 + kl_], b1_, chl);                       \
      clh = MFMA32(al[(SUB) * 8 + kl_], b0_, clh);                       \
    }                                                                    \
  }

// counted wait (never drains to 0 in steady state) + bare barrier + sched fence
#define PIPE_SYNC(N)                                                     \
  asm volatile("s_waitcnt vmcnt(" #N ")" ::: "memory");                  \
  __builtin_amdgcn_s_barrier();                                          \
  __builtin_amdgcn_sched_barrier(0);

// K2: fused e_proj (bf16x3, 32x32x16 MFMA) + tanh + v-dot -> scores[b][s]
// Wave owns 32 consecutive sb-rows, full K=512 A hi/lo in regs.
// B-fragments: 4x16KB LDS ring, sub-phase = 8 ks, stage lead = 3 sub-phases,
// counted vmcnt(8) + bare s_barrier per sub-phase (T3+T4).
__global__ __launch_bounds__(256, 1) void k_scores(const float* __restrict__ enc,
                                                   const char* __restrict__ WHb,
                                                   const char* __restrict__ WLb,
                                                   const float* __restrict__ hprojT,
                                                   const float* __restrict__ vW,
                                                   float* __restrict__ scores) {
  __shared__ char Bb[4 * 16384];
  int t = threadIdx.x;
  int w = t >> 6, lane = t & 63;
  int wbase = blockIdx.x * 128 + w * 32;   // first sb-row (multiple of 32 -> b == m)
  int arow = wbase + (lane & 31);
  int half = lane >> 5;

  SSTAGE(0);
  SSTAGE(1);

  // A fragments hi/lo for all 32 k-steps: enc[arow][ks*16 + half*8 + j]
  // (consuming these loads retires stage 0/1 too — ring invariant holds)
  s16x8 ah[32], al[32];
  {
    const float* ap = enc + (size_t)arow * H + half * 8;
#pragma unroll
    for (int ks = 0; ks < 32; ++ks) {
      float4 x0 = *(const float4*)(ap + ks * 16);
      float4 x1 = *(const float4*)(ap + ks * 16 + 4);
      float xs[8] = {x0.x, x0.y, x0.z, x0.w, x1.x, x1.y, x1.z, x1.w};
      s16x8 h, l;
#pragma unroll
      for (int j = 0; j < 8; ++j) {
        unsigned short hb = f2bf(xs[j]);
        h[j] = (short)hb;
        l[j] = (short)f2bf(xs[j] - bf2f(hb));
      }
      ah[ks] = h;
      al[ks] = l;
    }
  }

  SSTAGE(2);

  float pr[16];
#pragma unroll
  for (int r = 0; r < 16; ++r) pr[r] = 0.f;

  __builtin_amdgcn_s_barrier();        // stage-0 data visible to all waves
  __builtin_amdgcn_sched_barrier(0);

  for (int n = 0; n < 15; ++n) {
    // hproj/vW loads issued BEFORE this n's stages: their (compiler) wait at the
    // tail only forces older, already-retired stages — pipeline stays deep.
    int o = n * 32 + (lane & 31);
    float vw = vW[o];
    const float4* hp4 = (const float4*)(hprojT + o * B + half * 4);
    float4 h0 = hp4[0], h1 = hp4[2], h2 = hp4[4], h3 = hp4[6];
    f32x16 chh = {}, chl = {}, clh = {};
    int q = 4 * n;
    SSTAGE(q + 3); COMPUTE8(q + 0, 0); PIPE_SYNC(8)
    SSTAGE(q + 4); COMPUTE8(q + 1, 1); PIPE_SYNC(8)
    SSTAGE(q + 5); COMPUTE8(q + 2, 2); PIPE_SYNC(8)
    SSTAGE(q + 6); COMPUTE8(q + 3, 3);
    {
      float hr[16] = {h0.x, h0.y, h0.z, h0.w, h1.x, h1.y, h1.z, h1.w,
                      h2.x, h2.y, h2.z, h2.w, h3.x, h3.y, h3.z, h3.w};
#pragma unroll
      for (int r = 0; r < 16; ++r) {
        float e = (chh[r] + chl[r]) + clh[r] + hr[r];
        pr[r] += vw * tanh_fast(e);
      }
    }
    PIPE_SYNC(8)
  }

  // n = 15 epilogue: last stage is q=63; drain 8 -> 8 -> 0
  {
    int o = 15 * 32 + (lane & 31);
    float vw = vW[o];
    const float4* hp4 = (const float4*)(hprojT + o * B + half * 4);
    float4 h0 = hp4[0], h1 = hp4[2], h2 = hp4[4], h3 = hp4[6];
    f32x16 chh = {}, chl = {}, clh = {};
    SSTAGE(63);    COMPUTE8(60, 0); PIPE_SYNC(8)
    COMPUTE8(61, 1); PIPE_SYNC(8)
    COMPUTE8(62, 2); PIPE_SYNC(0)
    COMPUTE8(63, 3);
    {
      float hr[16] = {h0.x, h0.y, h0.z, h0.w, h1.x, h1.y, h1.z, h1.w,
                      h2.x, h2.y, h2.z, h2.w, h3.x, h3.y, h3.z, h3.w};
#pragma unroll
      for (int r = 0; r < 16; ++r) {
        float e = (chh[r] + chl[r]) + clh[r] + hr[r];
        pr[r] += vw * tanh_fast(e);
      }
    }
  }

  // reduce each pr[r] over the 32 col-lanes; lanes 0 and 32 hold results
#pragma unroll
  for (int off = 1; off < 32; off <<= 1) {
#pragma unroll
    for (int r = 0; r < 16; ++r) pr[r] += __shfl_xor(pr[r], off);
  }
  if ((lane & 31) == 0) {
    int srow = wbase >> 5;   // same s for all 32 rows of this wave
#pragma unroll
    for (int r = 0; r < 16; ++r) {
      int m = (r & 3) + 8 * (r >> 2) + 4 * half;  // row in wave = b index
      scores[(size_t)m * S + srow] = pr[r];
    }
  }
}

// K3: softmax over s for each b
__global__ __launch_bounds__(256) void k_softmax(const float* __restrict__ scores,
                                                 float* __restrict__ outw) {
  int b = blockIdx.x, t = threadIdx.x;
  const float* row = scores + (size_t)b * S;
  float* wrow = outw + (size_t)b * S;
  float m = -1e30f;
  for (int s = t; s < S; s += 256) m = fmaxf(m, row[s]);
#pragma unroll
  for (int off = 32; off; off >>= 1) m = fmaxf(m, __shfl_xor(m, off));
  __shared__ float red[4];
  __shared__ float red2[4];
  int wv = t >> 6, ln = t & 63;
  if (ln == 0) red[wv] = m;
  __syncthreads();
  m = fmaxf(fmaxf(red[0], red[1]), fmaxf(red[2], red[3]));
  float sum = 0.f;
  for (int s = t; s < S; s += 256) {
    float e = __expf(row[s] - m);
    wrow[s] = e;
    sum += e;
  }
#pragma unroll
  for (int off = 32; off; off >>= 1) sum += __shfl_xor(sum, off);
  if (ln == 0) red2[wv] = sum;
  __syncthreads();
  sum = red2[0] + red2[1] + red2[2] + red2[3];
  float inv = 1.f / sum;
  for (int s = t; s < S; s += 256) wrow[s] *= inv;
}

// K4: partial context sums over s-chunks: part[b][sc][h], float2-vectorized
__global__ __launch_bounds__(256) void k_ctxpart(const float* __restrict__ enc,
                                                 const float* __restrict__ w,
                                                 float* __restrict__ part) {
  int b = blockIdx.x, sc = blockIdx.y, t = threadIdx.x;
  const float* wrow = w + (size_t)b * S + sc * (S / NSC);
  float2 acc = {0.f, 0.f};
  for (int ss = 0; ss < S / NSC; ss += 2) {
    int s = sc * (S / NSC) + ss;
    float w0 = wrow[ss], w1 = wrow[ss + 1];
    float2 e0 = ((const float2*)(enc + ((size_t)s * B + b) * H))[t];
    float2 e1 = ((const float2*)(enc + ((size_t)(s + 1) * B + b) * H))[t];
    acc.x = fmaf(w0, e0.x, acc.x);
    acc.y = fmaf(w0, e0.y, acc.y);
    acc.x = fmaf(w1, e1.x, acc.x);
    acc.y = fmaf(w1, e1.y, acc.y);
  }
  ((float2*)(part + ((size_t)b * NSC + sc) * H))[t] = acc;
}

// K5: reduce partials -> context[b][h]
__global__ __launch_bounds__(256) void k_ctxsum(const float* __restrict__ part,
                                                float* __restrict__ ctx) {
  int idx = blockIdx.x * 256 + threadIdx.x;
  int b = idx >> 9, h = idx & 511;
  float sum = 0.f;
#pragma unroll
  for (int sc = 0; sc < NSC; ++sc) sum += part[((size_t)b * NSC + sc) * H + h];
  ctx[idx] = sum;
}

extern "C" void kernel_launch(void* const* d_in, const int* in_sizes, int n_in,
                              void* d_out, int out_size, void* d_ws, size_t ws_size,
                              hipStream_t stream) {
  const float* hidden = (const float*)d_in[0];   // (B,H)
  const float* enc    = (const float*)d_in[1];   // (S,B,H)
  const float* W      = (const float*)d_in[2];   // (H, 2H)
  const float* bias   = (const float*)d_in[3];   // (H,)
  const float* vW     = (const float*)d_in[4];   // (1,H)

  float* out   = (float*)d_out;
  float* ctx   = out;            // B*H
  float* attnw = out + B * H;    // B*S

  float* ws      = (float*)d_ws;
  float* hprojT  = ws;                      // B*H     = 16384 f (stored [o][b])
  float* scores  = ws + B * H;              // B*S     = 131072 f
  // union region (1 MB): WeFrag hi/lo during k_scores, then part for context
  float* region = scores + (size_t)B * S;   // 262144 f = 1 MB
  unsigned short* WH = (unsigned short*)region;                 // 512 KB
  unsigned short* WL = (unsigned short*)(region + 131072);      // 512 KB
  float* part = region;                                         // B*NSC*H

  k_wfrag<<<128, 256, 0, stream>>>(W, WH, WL);
  k_hproj<<<256, 256, 0, stream>>>(hidden, W, bias, hprojT);
  k_scores<<<(S * B) / 128, 256, 0, stream>>>(enc, (const char*)WH, (const char*)WL,
                                              hprojT, vW, scores);
  k_softmax<<<B, 256, 0, stream>>>(scores, attnw);
  k_ctxpart<<<dim3(B, NSC), 256, 0, stream>>>(enc, attnw, part);
  k_ctxsum<<<(B * H) / 256, 256, 0, stream>>>(part, ctx);
}